// Round 5
// baseline (348.044 us; speedup 1.0000x reference)
//
#include <hip/hip_runtime.h>
#include <hip/hip_bf16.h>
#include <stdint.h>

// MoE (E=16, D=1024, H=2048, K=2, T=2048), routed bf16-MFMA.
// R5: "flatmm" structure — NO LDS, NO barriers, NO inline asm in the GEMMs.
// Weights (f32, the only cold data) stream directly to registers as the MFMA
// A-operand (cvt->bf16 in-reg); activations (bf16, L2-resident) gather
// directly to registers as the B-operand. Each wave owns a 32x128 output
// tile, K-loop with depth-2 register prefetch; waves fully independent.

#define E_ 16
#define D_ 1024
#define H_ 2048
#define K_ 2
#define T_ 2048
#define NP_ (T_ * K_)     // 4096 token-expert pairs
#define MTS_ 48           // max token-tiles: sum ceil(ne/128) <= 48

using short8 = __attribute__((ext_vector_type(8))) short;
using f32x4  = __attribute__((ext_vector_type(4))) float;

__device__ __forceinline__ unsigned short f2bf(float f) {
  union { float f; unsigned u; } x; x.f = f;
  unsigned r = x.u + 0x7fffu + ((x.u >> 16) & 1u);   // RNE
  return (unsigned short)(r >> 16);
}

// gelu(tanh approx) = x * sigmoid(1.595769...*(x + 0.044715 x^3))
__device__ __forceinline__ float gelu_f(float x) {
  float u = 1.5957691216057308f * (x + 0.044715f * x * x * x);
  return x / (1.f + __expf(-u));
}

__global__ void cvt_kernel(const float* __restrict__ src,
                           unsigned short* __restrict__ dst, int n4) {
  int stride = gridDim.x * blockDim.x;
  for (int i = blockIdx.x * blockDim.x + threadIdx.x; i < n4; i += stride) {
    float4 v = reinterpret_cast<const float4*>(src)[i];
    ushort4 o = make_ushort4(f2bf(v.x), f2bf(v.y), f2bf(v.z), f2bf(v.w));
    reinterpret_cast<ushort4*>(dst)[i] = o;
  }
}

__global__ void route_kernel(const int* __restrict__ gidx,
                             int* __restrict__ rows,
                             int* __restrict__ offsets,
                             int2* __restrict__ tiles) {
  __shared__ int cnt[E_], cur[E_];
  int tid = threadIdx.x;
  if (tid < E_) cnt[tid] = 0;
  __syncthreads();
  for (int p = tid; p < NP_; p += blockDim.x) atomicAdd(&cnt[gidx[p]], 1);
  __syncthreads();
  if (tid == 0) {
    int acc = 0;
    for (int e = 0; e < E_; ++e) { offsets[e] = acc; cur[e] = acc; acc += cnt[e]; }
    offsets[E_] = acc;
    int k = 0;
    for (int e = 0; e < E_; ++e)
      for (int m = offsets[e]; m < offsets[e] + cnt[e]; m += 128)
        tiles[k++] = make_int2(e, m);
    for (; k < MTS_; ++k) tiles[k] = make_int2(-1, 0);
  }
  __syncthreads();
  for (int p = tid; p < NP_; p += blockDim.x) {
    int e = gidx[p];
    int pos = atomicAdd(&cur[e], 1);
    rows[pos] = p;
  }
}

// Flat register GEMM (transposed): out[wrow, tok] = W[wrow,:] . Act[tok,:].
// Block = 4 waves; wave w owns rows [bx*128 + w*32, +32) x 128 tokens of one
// token-tile. A-frag: lane(fr,fh) holds W[row16base+fr][k + fh*8 ..+7] (f32->
// bf16). B-frag: lane(fr,fh) holds Act[tok16base+fr][k + fh*8 ..+7] (bf16).
// C/D: row = base + fh*4 + j, col(token) = tok16base + fr (m89-verified map).
template<bool IS1>
__global__ __launch_bounds__(256, 2)
void moe_flat(const unsigned short* __restrict__ Bsrc,  // xb (IS1) or h
              const float* __restrict__ W,              // w1 or w2 (f32)
              const float* __restrict__ bias,           // [E][NN]
              const int* __restrict__ rows,
              const int* __restrict__ offsets,
              const int2* __restrict__ tiles,
              const float* __restrict__ score,          // [T*K]
              unsigned short* __restrict__ Hout,        // h (IS1)
              float* __restrict__ Yout)                 // y (!IS1)
{
  constexpr int KD = IS1 ? D_ : H_;   // contraction dim
  constexpr int NN = IS1 ? H_ : D_;   // output (weight-row) dim
  constexpr int NT = KD / 32;         // 32 or 64 K-steps

  const int2 tile = tiles[blockIdx.y];
  const int e = tile.x;
  if (e < 0) return;
  const int s0   = tile.y;            // token-tile base (routed slot)
  const int send = offsets[e + 1];

  const int tid = threadIdx.x, lane = tid & 63, wid = tid >> 6;
  const int fr = lane & 15, fh = lane >> 4;

  const int abase = blockIdx.x * 128 + wid * 32;   // weight-row base of wave

  // A pointers: two 16-row fragments (mi = 0,1), this lane's row = +fr.
  const float* gA0 = W + ((size_t)e * NN + abase + fr) * KD + fh * 8;
  const float* gA1 = gA0 + (size_t)16 * KD;

  // B element-offsets: 8 token fragments (ni), this lane's token = +fr.
  int boff[8];
#pragma unroll
  for (int ni = 0; ni < 8; ++ni) {
    int slot = s0 + ni * 16 + fr;
    int cs   = slot < send ? slot : (send - 1);
    int br   = IS1 ? (rows[cs] >> 1) : cs;   // token id or h row
    boff[ni] = br * KD;
  }
  const unsigned short* gBb = Bsrc + fh * 8;

  f32x4 acc[2][8] = {};
  short8 b0[8], b1[8];
  float4 a0[2][2], a1[2][2];

  auto loadB = [&](short8* b, int k0) {
#pragma unroll
    for (int ni = 0; ni < 8; ++ni)
      b[ni] = *reinterpret_cast<const short8*>(gBb + boff[ni] + k0);
  };
  auto loadA = [&](float4 (*a)[2], int k0) {
    a[0][0] = *reinterpret_cast<const float4*>(gA0 + k0);
    a[0][1] = *reinterpret_cast<const float4*>(gA0 + k0 + 4);
    a[1][0] = *reinterpret_cast<const float4*>(gA1 + k0);
    a[1][1] = *reinterpret_cast<const float4*>(gA1 + k0 + 4);
  };
  auto step = [&](float4 (*a)[2], short8* b) {
#pragma unroll
    for (int mi = 0; mi < 2; ++mi) {
      short8 av;
      const float* f0 = &a[mi][0].x;
      const float* f1 = &a[mi][1].x;
#pragma unroll
      for (int q = 0; q < 4; ++q) {
        av[q]     = (short)f2bf(f0[q]);
        av[4 + q] = (short)f2bf(f1[q]);
      }
#pragma unroll
      for (int ni = 0; ni < 8; ++ni)
        acc[mi][ni] = __builtin_amdgcn_mfma_f32_16x16x32_bf16(
            av, b[ni], acc[mi][ni], 0, 0, 0);
    }
  };

  // Depth-2 register prefetch; compiler inserts counted waitcnts.
  loadB(b0, 0);  loadA(a0, 0);
  loadB(b1, 32); loadA(a1, 32);

  for (int t = 0; t < NT; t += 2) {
    step(a0, b0);
    if (t + 2 < NT) { loadB(b0, (t + 2) * 32); loadA(a0, (t + 2) * 32); }
    step(a1, b1);
    if (t + 3 < NT) { loadB(b1, (t + 3) * 32); loadA(a1, (t + 3) * 32); }
  }

  // Epilogue: lane holds rows abase+mi*16+fh*4+0..3 (contiguous), token col
  // s0+ni*16+fr. GEMM1: h[slot][hcol] bf16 (8B stores). GEMM2: y[pair][dcol]
  // f32 (16B stores), scaled by gate score.
#pragma unroll
  for (int mi = 0; mi < 2; ++mi) {
    const int cb = abase + mi * 16 + fh * 4;
    float4 bs = *reinterpret_cast<const float4*>(bias + (size_t)e * NN + cb);
#pragma unroll
    for (int ni = 0; ni < 8; ++ni) {
      int slot = s0 + ni * 16 + fr;
      if (slot >= send) continue;
      if (IS1) {
        ushort4 hv;
        hv.x = f2bf(gelu_f(acc[mi][ni][0] + bs.x));
        hv.y = f2bf(gelu_f(acc[mi][ni][1] + bs.y));
        hv.z = f2bf(gelu_f(acc[mi][ni][2] + bs.z));
        hv.w = f2bf(gelu_f(acc[mi][ni][3] + bs.w));
        *reinterpret_cast<ushort4*>(Hout + (size_t)slot * H_ + cb) = hv;
      } else {
        int pair = rows[slot];
        float sc = score[pair];
        float4 yv;
        yv.x = (acc[mi][ni][0] + bs.x) * sc;
        yv.y = (acc[mi][ni][1] + bs.y) * sc;
        yv.z = (acc[mi][ni][2] + bs.z) * sc;
        yv.w = (acc[mi][ni][3] + bs.w) * sc;
        *reinterpret_cast<float4*>(Yout + (size_t)pair * D_ + cb) = yv;
      }
    }
  }
}

__global__ void combine_kernel(const float* __restrict__ y,
                               float* __restrict__ out) {
  const int DQ = D_ / 4;
  int i = blockIdx.x * blockDim.x + threadIdx.x;   // [0, T_*D_/4)
  int t = i / DQ, d = i % DQ;
  const float4* y4 = reinterpret_cast<const float4*>(y);
  float4 a = y4[(size_t)(2 * t) * DQ + d];
  float4 b = y4[(size_t)(2 * t + 1) * DQ + d];
  reinterpret_cast<float4*>(out)[i] =
      make_float4(a.x + b.x, a.y + b.y, a.z + b.z, a.w + b.w);
}

extern "C" void kernel_launch(void* const* d_in, const int* in_sizes, int n_in,
                              void* d_out, int out_size, void* d_ws, size_t ws_size,
                              hipStream_t stream) {
  const float* inp    = (const float*)d_in[0];
  const int*   gidx   = (const int*)d_in[1];
  const float* gscore = (const float*)d_in[2];
  const float* w1     = (const float*)d_in[3];
  const float* b1     = (const float*)d_in[4];
  const float* w2     = (const float*)d_in[5];
  const float* b2     = (const float*)d_in[6];
  float* out = (float*)d_out;

  char* ws = (char*)d_ws;
  size_t o = 0;
  auto alloc = [&](size_t bytes) {
    void* p = ws + o;
    o = (o + bytes + 255) & ~(size_t)255;
    return p;
  };
  unsigned short* xb   = (unsigned short*)alloc((size_t)T_ * D_ * 2);
  unsigned short* hbuf = (unsigned short*)alloc((size_t)NP_ * H_ * 2);
  float*          ybuf = (float*)alloc((size_t)NP_ * D_ * 4);
  int*            rows = (int*)alloc(NP_ * 4);
  int*         offsets = (int*)alloc((E_ + 1) * 4);
  int2*          tiles = (int2*)alloc(MTS_ * 8);

  cvt_kernel<<<dim3(512), dim3(256), 0, stream>>>(inp, xb, T_ * D_ / 4);
  route_kernel<<<dim3(1), dim3(256), 0, stream>>>(gidx, rows, offsets, tiles);

  moe_flat<true><<<dim3(H_ / 128, MTS_), dim3(256), 0, stream>>>(
      xb, w1, b1, rows, offsets, tiles, gscore, hbuf, (float*)nullptr);
  moe_flat<false><<<dim3(D_ / 128, MTS_), dim3(256), 0, stream>>>(
      hbuf, w2, b2, rows, offsets, tiles, gscore, (unsigned short*)nullptr, ybuf);

  combine_kernel<<<dim3(T_ * D_ / 4 / 256), dim3(256), 0, stream>>>(ybuf, out);
}